// Round 3
// baseline (91.138 us; speedup 1.0000x reference)
//
#include <hip/hip_runtime.h>
#include <hip/hip_cooperative_groups.h>

namespace cg = cooperative_groups;

// Problem geometry (fixed by reference): rgbd [4,4,512,512] f32, channels 0..2.
#define HW        262144          // 512*512
#define PER_BATCH 786432          // 3*HW (channels 0..2 contiguous per batch)
#define NVEC      786432          // used floats / 4
#define KSUB      8               // sub-bins per unit bin
#define NSUB      2048            // 256*KSUB
#define NHIST     6144            // 3*NSUB
#define NPAD      6336            // NHIST + NHIST/32 (skewed layout)
#define WIN       64              // window half-width in sub-bins (|v-x| <= 8)
#define NTAP      (2*WIN + 1)
#define P_INV     (1.0f / 1048576.0f)
#define NBLK      256             // == CU count -> co-resident for grid.sync
#define NTHR      1024

// skewed LDS index: insert one pad float every 32 -> stride-8 wave access
// becomes <=2-way bank conflict (free) instead of 16-way (~5.7x, m136)
__device__ __forceinline__ int skew(int a) { return a + (a >> 5); }

__global__ __launch_bounds__(NTHR) void fused_kernel(const float* __restrict__ in,
                                                     unsigned* __restrict__ partial,
                                                     float* __restrict__ fhist,
                                                     float* __restrict__ out) {
    cg::grid_group grid = cg::this_grid();
    __shared__ unsigned lhist[NHIST];       // 24 KB
    __shared__ float red2[4][256];          //  4 KB (phase 2)
    __shared__ float fhp[NPAD];             // ~25 KB (phase 3, skewed)
    __shared__ float w[NTAP];
    __shared__ float red[NTHR];

    const int tid = threadIdx.x;
    const int bid = blockIdx.x;

    // ---------------- phase 1: per-block sub-bin histogram -----------------
    for (int i = tid; i < NHIST; i += NTHR) lhist[i] = 0u;
    __syncthreads();

    const int stride = NBLK * NTHR;
    for (int idx = bid * NTHR + tid; idx < NVEC; idx += stride) {
        const int u = idx * 4;                 // compact float index (3-ch data)
        const int b = u / PER_BATCH;           // batch (magic-mul)
        const int r = u - b * PER_BATCH;       // offset within batch's 3-ch block
        const int ch = r >> 18;                // / HW -> channel 0..2
        const float4 v = *reinterpret_cast<const float4*>(in + (size_t)b * (4 * HW) + r);
        const float vals[4] = {v.x, v.y, v.z, v.w};
#pragma unroll
        for (int j = 0; j < 4; ++j) {
            // q = round(127.5*(x+1)*KSUB) = round(1020*x + 1020)
            int q = __float2int_rn(fmaf(vals[j], 1020.0f, 1020.0f));
            q = min(max(q, 0), NSUB - 1);
            atomicAdd(&lhist[ch * NSUB + q], 1u);
        }
    }
    __syncthreads();
    {
        unsigned* dst = partial + (size_t)bid * NHIST;
        for (int i = tid; i < NHIST; i += NTHR) dst[i] = lhist[i];
    }

    grid.sync();

    // ---------------- phase 2: column reduce (blocks 0..23) ----------------
    if (bid < 24) {
        const int col = bid * 256 + (tid & 255);   // coalesced across wave
        const int rg  = tid >> 8;                  // 0..3 row groups
        unsigned s = 0;
        for (int r = rg * 64; r < rg * 64 + 64; ++r)
            s += partial[(size_t)r * NHIST + col];
        red2[rg][tid & 255] = (float)s;
        __syncthreads();
        if (rg == 0)
            fhist[col] = red2[0][tid] + red2[1][tid] + red2[2][tid] + red2[3][tid];
    }

    grid.sync();

    // ---------------- phase 3: Gaussian conv + L2 loss (block 0) -----------
    if (bid == 0) {
        for (int i = tid; i < NHIST; i += NTHR) fhp[skew(i)] = fhist[i];
        for (int i = tid; i < NTAP; i += NTHR) {
            const float d = (float)(i - WIN) * (1.0f / (float)KSUB);
            w[i] = 0.5f * expf(-0.5f * d * d);
        }
        __syncthreads();

        float acc = 0.0f;
        if (tid < 768) {                       // 3 channels * 256 bins
            const int c = tid >> 8;
            const int vbin = tid & 255;
            const int center = vbin * KSUB;
            const int q0 = max(center - WIN, 0);
            const int q1 = min(center + WIN, NSUB - 1);
            float s = 0.0f;
            for (int q = q0; q <= q1; ++q)
                s += fhp[skew(c * NSUB + q)] * w[q - center + WIN];
            const float d = s * P_INV - (1.0f / 256.0f);
            acc = d * d;
        }
        red[tid] = acc;
        __syncthreads();
        for (int off = 512; off > 0; off >>= 1) {
            if (tid < off) red[tid] += red[tid + off];
            __syncthreads();
        }
        if (tid == 0) out[0] = red[0];
    }
}

// ---------------------------------------------------------------------------
extern "C" void kernel_launch(void* const* d_in, const int* in_sizes, int n_in,
                              void* d_out, int out_size, void* d_ws, size_t ws_size,
                              hipStream_t stream) {
    const float* in = (const float*)d_in[0];
    float* out = (float*)d_out;
    unsigned* partial = (unsigned*)d_ws;                       // 256*6144 u32 = 6 MB
    float* fhist = (float*)((char*)d_ws + (size_t)NBLK * NHIST * sizeof(unsigned));

    void* args[] = {(void*)&in, (void*)&partial, (void*)&fhist, (void*)&out};
    hipLaunchCooperativeKernel((const void*)fused_kernel, dim3(NBLK), dim3(NTHR),
                               args, 0, stream);
}

// Round 4
// 20.409 us; speedup vs baseline: 4.4656x; 4.4656x over previous
//
#include <hip/hip_runtime.h>

// Problem geometry (fixed by reference): rgbd [4,4,512,512] f32, channels 0..2.
#define HW        262144          // 512*512
#define PER_BATCH 786432          // 3*HW (channels 0..2 contiguous per batch)
#define NVEC      786432          // used floats / 4
#define KSUB      8               // sub-bins per unit bin
#define NSUB      2048            // 256*KSUB
#define NHIST     6144            // 3*NSUB
#define WIN       64              // window half-width in sub-bins (|v-x| <= 8)
#define NTAP      129
#define P_INV     (1.0f / 1048576.0f)
#define TARGET    (1.0f / 256.0f)
#define NPART     256             // hist blocks
#define COLS      384             // sub-bin window per conv block (377 needed)

// ---------------- Kernel 1: per-block sub-bin histogram --------------------
__global__ __launch_bounds__(1024) void hist_kernel(const float* __restrict__ in,
                                                    unsigned* __restrict__ partial,
                                                    float* __restrict__ out) {
    __shared__ unsigned lhist[NHIST];
    for (int i = threadIdx.x; i < NHIST; i += 1024) lhist[i] = 0u;
    if (blockIdx.x == 0 && threadIdx.x == 0) out[0] = 0.0f;  // replaces memset node
    __syncthreads();

    const int stride = NPART * 1024;
    for (int idx = blockIdx.x * 1024 + threadIdx.x; idx < NVEC; idx += stride) {
        const int u = idx * 4;                 // compact float index over 3-ch data
        const int b = u / PER_BATCH;           // batch (magic-mul)
        const int r = u - b * PER_BATCH;       // offset within batch's 3-ch block
        const int ch = r >> 18;                // / HW -> channel 0..2
        const float4 v = *reinterpret_cast<const float4*>(in + (size_t)b * (4 * HW) + r);
        const float vals[4] = {v.x, v.y, v.z, v.w};
#pragma unroll
        for (int j = 0; j < 4; ++j) {
            // q = round(127.5*(x+1)*KSUB) = round(1020*x + 1020)
            int q = __float2int_rn(fmaf(vals[j], 1020.0f, 1020.0f));
            q = min(max(q, 0), NSUB - 1);
            atomicAdd(&lhist[ch * NSUB + q], 1u);
        }
    }
    __syncthreads();

    unsigned* dst = partial + (size_t)blockIdx.x * NHIST;
    for (int i = threadIdx.x; i < 1024 * 6; i += 1024) dst[i] = lhist[i];
    for (int i = 1024 * 6 + threadIdx.x; i < NHIST; i += 1024) dst[i] = lhist[i];
}

// ---------------- Kernel 2: windowed reduce + Gaussian conv + loss ---------
// 24 blocks; block b owns 32 output bins of channel b>>3, window of 384 sub-bins.
__global__ __launch_bounds__(512) void reduce_conv_kernel(const unsigned* __restrict__ partial,
                                                          float* __restrict__ out) {
    __shared__ float fh[COLS];
    __shared__ float w[NTAP];
    __shared__ float lsum[8];

    const int bid = blockIdx.x;            // 0..23
    const int tid = threadIdx.x;
    const int c = bid >> 3;                // channel 0..2
    const int obase = (bid & 7) * 32;      // first vbin (within channel)
    int wlo = obase * 8 - 64;              // window start (sub-bins, in-channel)
    wlo = min(max(wlo, 0), NSUB - COLS);   // always a multiple of 64 -> 256B aligned

    if (tid < NTAP) {
        const float d = (float)(tid - WIN) * 0.125f;
        w[tid] = 0.5f * expf(-0.5f * d * d);
    }

    // windowed column reduce over 256 partials: threads 0..383, one column each
    if (tid < COLS) {
        const unsigned* p = partial + (size_t)(c * NSUB + wlo) + tid;
        unsigned s = 0;
#pragma unroll 8
        for (int r = 0; r < NPART; ++r) s += p[(size_t)r * NHIST];
        fh[tid] = (float)s;
    }
    __syncthreads();

    // conv: threads 0..255 = 32 outputs x 8 sub-lanes
    float myloss = 0.0f;
    if (tid < 256) {
        const int o = tid >> 3;            // 0..31
        const int sub = tid & 7;
        const int center = (obase + o) * 8;
        float s = 0.0f;
#pragma unroll
        for (int i = 0; i < 17; ++i) {
            const int widx = sub + 8 * i;          // tap index 0..135 (valid <=128)
            const int q = center - WIN + widx;     // in-channel sub-bin
            if (widx <= 128 && q >= 0 && q < NSUB)
                s += fh[q - wlo] * w[widx];
        }
        s += __shfl_xor(s, 1);
        s += __shfl_xor(s, 2);
        s += __shfl_xor(s, 4);                     // all 8 lanes hold the tap-sum
        if (sub == 0) {
            const float d = s * P_INV - TARGET;
            myloss = d * d;
        }
    }
    // wave-level sum of the (masked) per-output losses
    myloss += __shfl_xor(myloss, 8);
    myloss += __shfl_xor(myloss, 16);
    myloss += __shfl_xor(myloss, 32);
    if ((tid & 63) == 0) lsum[tid >> 6] = myloss;
    __syncthreads();
    if (tid == 0) {
        float t = 0.0f;
#pragma unroll
        for (int i = 0; i < 8; ++i) t += lsum[i];
        atomicAdd(out, t);                 // out zeroed by hist_kernel (stream-ordered)
    }
}

// ---------------------------------------------------------------------------
extern "C" void kernel_launch(void* const* d_in, const int* in_sizes, int n_in,
                              void* d_out, int out_size, void* d_ws, size_t ws_size,
                              hipStream_t stream) {
    const float* in = (const float*)d_in[0];
    float* out = (float*)d_out;
    unsigned* partial = (unsigned*)d_ws;   // NPART*NHIST u32 = 6 MB

    hist_kernel<<<NPART, 1024, 0, stream>>>(in, partial, out);
    reduce_conv_kernel<<<24, 512, 0, stream>>>(partial, out);
}

// Round 5
// 15.707 us; speedup vs baseline: 5.8022x; 1.2993x over previous
//
#include <hip/hip_runtime.h>

// Problem geometry (fixed by reference): rgbd [4,4,512,512] f32, channels 0..2.
#define HW        262144          // 512*512
#define PER_BATCH 786432          // 3*HW (channels 0..2 contiguous per batch)
#define NVEC      786432          // used floats / 4
#define NSUB      2048            // 256 bins * 8 sub-bins
#define NHIST     6144            // 3*NSUB
#define HWORDS    3072            // NHIST/2 (u16-pair packed)
#define WIN       64              // window half-width in sub-bins (|v-x| <= 8)
#define NTAP      129
#define P_INV     (1.0f / 1048576.0f)
#define TARGET    (1.0f / 256.0f)
#define NPART     256             // hist blocks
#define COLS      192             // sub-bin window per conv block (185 needed)
#define CBLK      96              // conv blocks: 3 ch * 32, 8 output bins each

// ---------------- Kernel 1: per-block sub-bin histogram, u16-packed --------
__global__ __launch_bounds__(1024) void hist_kernel(const float* __restrict__ in,
                                                    unsigned* __restrict__ partial,
                                                    float* __restrict__ out) {
    __shared__ unsigned lhist[NHIST];
    for (int i = threadIdx.x; i < NHIST; i += 1024) lhist[i] = 0u;
    if (blockIdx.x == 0 && threadIdx.x == 0) out[0] = 0.0f;  // replaces memset node
    __syncthreads();

    const int stride = NPART * 1024;
    for (int idx = blockIdx.x * 1024 + threadIdx.x; idx < NVEC; idx += stride) {
        const int u = idx * 4;                 // compact float index over 3-ch data
        const int b = u / PER_BATCH;           // batch (magic-mul)
        const int r = u - b * PER_BATCH;       // offset within batch's 3-ch block
        const int ch = r >> 18;                // / HW -> channel 0..2
        const float4 v = *reinterpret_cast<const float4*>(in + (size_t)b * (4 * HW) + r);
        const float vals[4] = {v.x, v.y, v.z, v.w};
#pragma unroll
        for (int j = 0; j < 4; ++j) {
            // q = round(127.5*(x+1)*8) = round(1020*x + 1020)
            int q = __float2int_rn(fmaf(vals[j], 1020.0f, 1020.0f));
            q = min(max(q, 0), NSUB - 1);
            atomicAdd(&lhist[ch * NSUB + q], 1u);
        }
    }
    __syncthreads();

    // max count/bin/block = 49152 < 2^16 -> pack two u16 counts per word
    unsigned* dst = partial + (size_t)blockIdx.x * HWORDS;
    for (int i = threadIdx.x; i < HWORDS; i += 1024)
        dst[i] = (lhist[2 * i] & 0xFFFFu) | (lhist[2 * i + 1] << 16);
}

// ---------------- Kernel 2: windowed reduce + Gaussian conv + loss ---------
// 96 blocks x 1024 thr; block owns 8 output bins of one channel, 192-col window.
__global__ __launch_bounds__(1024) void reduce_conv_kernel(const unsigned* __restrict__ partial,
                                                           float* __restrict__ out) {
    __shared__ float fh4[4][COLS];
    __shared__ float fh[COLS];
    __shared__ float w[NTAP];
    __shared__ float osum[16];

    const int tid = threadIdx.x;
    const int bid = blockIdx.x;
    const int c = bid >> 5;                // channel 0..2
    const int obase = (bid & 31) * 8;      // first vbin (0..248)
    int wlo = obase * 8 - WIN;             // window start (sub-bins, in-channel)
    wlo = min(max(wlo, 0), NSUB - COLS);   // multiple of 64 -> even, aligned

    if (tid < NTAP) {
        const float d = (float)(tid - WIN) * 0.125f;
        w[tid] = 0.5f * expf(-0.5f * d * d);
    }

    // windowed column reduce: 4 row-groups x 96 threads x (2 cols, 64 rows each)
    const int rg = tid >> 8;               // 0..3
    const int t  = tid & 255;
    if (t < COLS / 2) {
        const unsigned* p = partial + (size_t)(c * NSUB + wlo) / 2 + t;
        unsigned s0 = 0, s1 = 0;
        const int r0 = rg * 64;
#pragma unroll 8
        for (int r = r0; r < r0 + 64; ++r) {
            const unsigned v = p[(size_t)r * HWORDS];
            s0 += v & 0xFFFFu;
            s1 += v >> 16;
        }
        fh4[rg][2 * t]     = (float)s0;
        fh4[rg][2 * t + 1] = (float)s1;
    }
    __syncthreads();
    if (tid < COLS)
        fh[tid] = fh4[0][tid] + fh4[1][tid] + fh4[2][tid] + fh4[3][tid];
    __syncthreads();

    // conv: 8 outputs x 64 lanes (tid < 512), <=3 taps/lane, full-wave reduce
    float s = 0.0f;
    const int o = tid >> 6;
    const int lane = tid & 63;
    if (tid < 512) {
        const int center = (obase + o) * 8;
#pragma unroll
        for (int i = 0; i < 3; ++i) {
            const int widx = lane + 64 * i;
            const int q = center - WIN + widx;
            if (widx < NTAP && q >= 0 && q < NSUB)
                s += fh[q - wlo] * w[widx];
        }
    }
    s += __shfl_xor(s, 1);  s += __shfl_xor(s, 2);  s += __shfl_xor(s, 4);
    s += __shfl_xor(s, 8);  s += __shfl_xor(s, 16); s += __shfl_xor(s, 32);
    float myloss = 0.0f;
    if (tid < 512 && lane == 0) {
        const float d = s * P_INV - TARGET;
        myloss = d * d;
    }
    if (lane == 0) osum[tid >> 6] = myloss;
    __syncthreads();
    if (tid == 0) {
        float tsum = 0.0f;
#pragma unroll
        for (int i = 0; i < 8; ++i) tsum += osum[i];
        atomicAdd(out, tsum);              // out zeroed by hist_kernel (stream-ordered)
    }
}

// ---------------------------------------------------------------------------
extern "C" void kernel_launch(void* const* d_in, const int* in_sizes, int n_in,
                              void* d_out, int out_size, void* d_ws, size_t ws_size,
                              hipStream_t stream) {
    const float* in = (const float*)d_in[0];
    float* out = (float*)d_out;
    unsigned* partial = (unsigned*)d_ws;   // NPART*HWORDS u32 = 3 MB

    hist_kernel<<<NPART, 1024, 0, stream>>>(in, partial, out);
    reduce_conv_kernel<<<CBLK, 1024, 0, stream>>>(partial, out);
}

// Round 6
// 14.528 us; speedup vs baseline: 6.2733x; 1.0812x over previous
//
#include <hip/hip_runtime.h>

// Problem geometry (fixed by reference): rgbd [4,4,512,512] f32, channels 0..2.
#define HW        262144          // 512*512
#define PER_BATCH 786432          // 3*HW (channels 0..2 contiguous per batch)
#define NVEC      786432          // used floats / 4
#define NSUB      2048            // 256 bins * 8 sub-bins
#define NHIST     6144            // 3*NSUB
#define HWORDS    3072            // NHIST/2 (u16-pair packed)
#define WIN       64              // window half-width in sub-bins (|v-x| <= 8)
#define NTAP      129
#define P_INV     (1.0f / 1048576.0f)
#define TARGET    (1.0f / 256.0f)
#define NPART     256             // hist blocks
#define COLS      192             // sub-bin window per conv block (185 needed)
#define CBLK      96              // conv blocks: 3 ch * 32, 8 output bins each

// ---------------- Kernel 1: per-block sub-bin histogram, u16-packed --------
__global__ __launch_bounds__(1024) void hist_kernel(const float* __restrict__ in,
                                                    unsigned* __restrict__ partial,
                                                    float* __restrict__ out) {
    __shared__ unsigned lhist[NHIST];
    for (int i = threadIdx.x; i < NHIST; i += 1024) lhist[i] = 0u;
    if (blockIdx.x == 0 && threadIdx.x == 0) out[0] = 0.0f;  // replaces memset node
    __syncthreads();

    const int stride = NPART * 1024;
    for (int idx = blockIdx.x * 1024 + threadIdx.x; idx < NVEC; idx += stride) {
        const int u = idx * 4;                 // compact float index over 3-ch data
        const int b = u / PER_BATCH;           // batch (magic-mul)
        const int r = u - b * PER_BATCH;       // offset within batch's 3-ch block
        const int ch = r >> 18;                // / HW -> channel 0..2
        const float4 v = *reinterpret_cast<const float4*>(in + (size_t)b * (4 * HW) + r);
        const float vals[4] = {v.x, v.y, v.z, v.w};
#pragma unroll
        for (int j = 0; j < 4; ++j) {
            // q = round(127.5*(x+1)*8) = round(1020*x + 1020)
            int q = __float2int_rn(fmaf(vals[j], 1020.0f, 1020.0f));
            q = min(max(q, 0), NSUB - 1);
            atomicAdd(&lhist[ch * NSUB + q], 1u);
        }
    }
    __syncthreads();

    // max count/bin/block = 12288 < 2^16 -> pack two u16 counts per word,
    // 8 counts -> one uint4 coalesced store
    if (threadIdx.x < 768) {
        const unsigned* src = &lhist[threadIdx.x * 8];
        uint4 v;
        v.x = (src[0] & 0xFFFFu) | (src[1] << 16);
        v.y = (src[2] & 0xFFFFu) | (src[3] << 16);
        v.z = (src[4] & 0xFFFFu) | (src[5] << 16);
        v.w = (src[6] & 0xFFFFu) | (src[7] << 16);
        reinterpret_cast<uint4*>(partial + (size_t)blockIdx.x * HWORDS)[threadIdx.x] = v;
    }
}

// ---------------- Kernel 2: windowed reduce + Gaussian conv + loss ---------
// 96 blocks x 1024 thr; block owns 8 output bins of one channel, 192-col window.
__global__ __launch_bounds__(1024) void reduce_conv_kernel(const unsigned* __restrict__ partial,
                                                           float* __restrict__ out) {
    __shared__ float fh8[8][COLS];         // 6 KB
    __shared__ float fh[COLS];
    __shared__ float w[NTAP];
    __shared__ float osum[16];

    const int tid = threadIdx.x;
    const int bid = blockIdx.x;
    const int c = bid >> 5;                // channel 0..2
    const int obase = (bid & 31) * 8;      // first vbin (0..248)
    int wlo = obase * 8 - WIN;             // window start (sub-bins, in-channel)
    wlo = min(max(wlo, 0), NSUB - COLS);   // multiple of 64 -> even, aligned

    if (tid < NTAP) {
        const float d = (float)(tid - WIN) * 0.125f;
        w[tid] = 0.5f * expf(-0.5f * d * d);
    }

    // windowed column reduce: 8 row-groups x 96 word-cols, 32 rows each,
    // fully unrolled -> 32 loads in flight per thread
    {
        const int rg = tid >> 7;           // 0..7
        const int t  = tid & 127;          // word-col
        if (t < COLS / 2) {
            const unsigned* p = partial + (size_t)(c * NSUB + wlo) / 2 + t
                              + (size_t)rg * 32 * HWORDS;
            unsigned s0 = 0, s1 = 0;
#pragma unroll
            for (int r = 0; r < 32; ++r) {
                const unsigned v = p[(size_t)r * HWORDS];
                s0 += v & 0xFFFFu;
                s1 += v >> 16;
            }
            fh8[rg][2 * t]     = (float)s0;
            fh8[rg][2 * t + 1] = (float)s1;
        }
    }
    __syncthreads();
    if (tid < COLS) {
        float s = 0.0f;
#pragma unroll
        for (int g = 0; g < 8; ++g) s += fh8[g][tid];
        fh[tid] = s;
    }
    __syncthreads();

    // conv: 8 outputs x 64 lanes (tid < 512), <=3 taps/lane, full-wave reduce
    float s = 0.0f;
    const int o = tid >> 6;
    const int lane = tid & 63;
    if (tid < 512) {
        const int center = (obase + o) * 8;
#pragma unroll
        for (int i = 0; i < 3; ++i) {
            const int widx = lane + 64 * i;
            const int q = center - WIN + widx;
            if (widx < NTAP && q >= 0 && q < NSUB)
                s += fh[q - wlo] * w[widx];
        }
    }
    s += __shfl_xor(s, 1);  s += __shfl_xor(s, 2);  s += __shfl_xor(s, 4);
    s += __shfl_xor(s, 8);  s += __shfl_xor(s, 16); s += __shfl_xor(s, 32);
    float myloss = 0.0f;
    if (tid < 512 && lane == 0) {
        const float d = s * P_INV - TARGET;
        myloss = d * d;
    }
    if (lane == 0) osum[tid >> 6] = myloss;
    __syncthreads();
    if (tid == 0) {
        float tsum = 0.0f;
#pragma unroll
        for (int i = 0; i < 8; ++i) tsum += osum[i];
        atomicAdd(out, tsum);              // out zeroed by hist_kernel (stream-ordered)
    }
}

// ---------------------------------------------------------------------------
extern "C" void kernel_launch(void* const* d_in, const int* in_sizes, int n_in,
                              void* d_out, int out_size, void* d_ws, size_t ws_size,
                              hipStream_t stream) {
    const float* in = (const float*)d_in[0];
    float* out = (float*)d_out;
    unsigned* partial = (unsigned*)d_ws;   // NPART*HWORDS u32 = 3 MB

    hist_kernel<<<NPART, 1024, 0, stream>>>(in, partial, out);
    reduce_conv_kernel<<<CBLK, 1024, 0, stream>>>(partial, out);
}

// Round 7
// 13.956 us; speedup vs baseline: 6.5305x; 1.0410x over previous
//
#include <hip/hip_runtime.h>

// Problem geometry (fixed by reference): rgbd [4,4,512,512] f32, channels 0..2.
#define HW        262144          // 512*512
#define PER_BATCH 786432          // 3*HW (channels 0..2 contiguous per batch)
#define NVEC      786432          // used floats / 4
#define NSUB      2048            // 256 bins * 8 sub-bins
#define NHIST     6144            // 3*NSUB
#define HWORDS    3072            // NHIST/2 (u16-pair packed)
#define WIN       64              // window half-width in sub-bins (|v-x| <= 8)
#define NTAP      129
#define P_INV     (1.0f / 1048576.0f)
#define TARGET    (1.0f / 256.0f)
#define NPART     256             // hist blocks
#define COLS      256             // sub-bin window per conv block (249 needed)
#define CBLK      48              // conv blocks: 3 ch * 16, 16 output bins each

// ---------------- Kernel 1: per-block sub-bin histogram, u16-packed --------
__global__ __launch_bounds__(1024) void hist_kernel(const float* __restrict__ in,
                                                    unsigned* __restrict__ partial,
                                                    float* __restrict__ out) {
    __shared__ unsigned lhist[NHIST];
    for (int i = threadIdx.x; i < NHIST; i += 1024) lhist[i] = 0u;
    if (blockIdx.x == 0 && threadIdx.x == 0) out[0] = 0.0f;  // replaces memset node
    __syncthreads();

    const int stride = NPART * 1024;
    for (int idx = blockIdx.x * 1024 + threadIdx.x; idx < NVEC; idx += stride) {
        const int u = idx * 4;                 // compact float index over 3-ch data
        const int b = u / PER_BATCH;           // batch (magic-mul)
        const int r = u - b * PER_BATCH;       // offset within batch's 3-ch block
        const int ch = r >> 18;                // / HW -> channel 0..2 (float4 never spans)
        const float4 v = *reinterpret_cast<const float4*>(in + (size_t)b * (4 * HW) + r);
        const float vals[4] = {v.x, v.y, v.z, v.w};
#pragma unroll
        for (int j = 0; j < 4; ++j) {
            // q = round(127.5*(x+1)*8) = round(1020*x + 1020)
            int q = __float2int_rn(fmaf(vals[j], 1020.0f, 1020.0f));
            q = min(max(q, 0), NSUB - 1);
            atomicAdd(&lhist[ch * NSUB + q], 1u);
        }
    }
    __syncthreads();

    // worst-case count/bin/block = 49152 < 2^16 -> pack two u16 counts/word,
    // 8 counts -> one uint4 coalesced store
    if (threadIdx.x < 768) {
        const unsigned* src = &lhist[threadIdx.x * 8];
        uint4 v;
        v.x = (src[0] & 0xFFFFu) | (src[1] << 16);
        v.y = (src[2] & 0xFFFFu) | (src[3] << 16);
        v.z = (src[4] & 0xFFFFu) | (src[5] << 16);
        v.w = (src[6] & 0xFFFFu) | (src[7] << 16);
        reinterpret_cast<uint4*>(partial + (size_t)blockIdx.x * HWORDS)[threadIdx.x] = v;
    }
}

// ---------------- Kernel 2: windowed reduce + Gaussian conv + loss ---------
// 48 blocks x 1024 thr; block owns 16 output bins of one channel, 256-col window.
__global__ __launch_bounds__(1024) void reduce_conv_kernel(const unsigned* __restrict__ partial,
                                                           float* __restrict__ out) {
    __shared__ float fh8[8][COLS];         // 8 KB
    __shared__ float fh[COLS];
    __shared__ float w[NTAP];
    __shared__ float osum[16];

    const int tid = threadIdx.x;
    const int bid = blockIdx.x;
    const int c = bid >> 4;                // channel 0..2
    const int obase = (bid & 15) * 16;     // first vbin (0..240)
    int wlo = obase * 8 - WIN;             // window start (sub-bins, in-channel)
    wlo = min(max(wlo, 0), NSUB - COLS);   // multiple of 64 -> even, aligned

    if (tid < NTAP) {
        const float d = (float)(tid - WIN) * 0.125f;
        w[tid] = 0.5f * expf(-0.5f * d * d);
    }

    // windowed column reduce: 8 row-groups x 128 word-cols, 32 rows each,
    // fully unrolled -> 32 loads in flight per thread
    {
        const int rg = tid >> 7;           // 0..7
        const int t  = tid & 127;          // word-col 0..127
        const unsigned* p = partial + (size_t)(c * NSUB + wlo) / 2 + t
                          + (size_t)rg * 32 * HWORDS;
        unsigned s0 = 0, s1 = 0;
#pragma unroll
        for (int r = 0; r < 32; ++r) {
            const unsigned v = p[(size_t)r * HWORDS];
            s0 += v & 0xFFFFu;
            s1 += v >> 16;
        }
        fh8[rg][2 * t]     = (float)s0;
        fh8[rg][2 * t + 1] = (float)s1;
    }
    __syncthreads();
    if (tid < COLS) {
        float s = 0.0f;
#pragma unroll
        for (int g = 0; g < 8; ++g) s += fh8[g][tid];
        fh[tid] = s;
    }
    __syncthreads();

    // conv: 16 outputs x 64 lanes (all 1024 threads), <=3 taps/lane
    float s = 0.0f;
    const int o = tid >> 6;                // 0..15
    const int lane = tid & 63;
    {
        const int center = (obase + o) * 8;
#pragma unroll
        for (int i = 0; i < 3; ++i) {
            const int widx = lane + 64 * i;
            const int q = center - WIN + widx;
            if (widx < NTAP && q >= 0 && q < NSUB)
                s += fh[q - wlo] * w[widx];
        }
    }
    s += __shfl_xor(s, 1);  s += __shfl_xor(s, 2);  s += __shfl_xor(s, 4);
    s += __shfl_xor(s, 8);  s += __shfl_xor(s, 16); s += __shfl_xor(s, 32);
    if (lane == 0) {
        const float d = s * P_INV - TARGET;
        osum[o] = d * d;
    }
    __syncthreads();
    if (tid == 0) {
        float tsum = 0.0f;
#pragma unroll
        for (int i = 0; i < 16; ++i) tsum += osum[i];
        atomicAdd(out, tsum);              // out zeroed by hist_kernel (stream-ordered)
    }
}

// ---------------------------------------------------------------------------
extern "C" void kernel_launch(void* const* d_in, const int* in_sizes, int n_in,
                              void* d_out, int out_size, void* d_ws, size_t ws_size,
                              hipStream_t stream) {
    const float* in = (const float*)d_in[0];
    float* out = (float*)d_out;
    unsigned* partial = (unsigned*)d_ws;   // NPART*HWORDS u32 = 3 MB

    hist_kernel<<<NPART, 1024, 0, stream>>>(in, partial, out);
    reduce_conv_kernel<<<CBLK, 1024, 0, stream>>>(partial, out);
}